// Round 13
// baseline (264.249 us; speedup 1.0000x reference)
//
#include <hip/hip_runtime.h>
#include <hip/hip_bf16.h>
#include <math.h>

// Problem constants
#define BB 32
#define LL 4100
#define SS 1024
#define EE 16
#define HH 4
#define DHD 4
#define NCC 10

// Native exp2: single v_exp_f32; libm exp2f lowers to ~30-inst OCML (R6 finding).
#define EXP2(x) __builtin_amdgcn_exp2f(x)

typedef __attribute__((ext_vector_type(8))) short short8v;   // 8 bf16 = 4 VGPR (MFMA A/B)
typedef __attribute__((ext_vector_type(4))) float float4v;   // MFMA C/D

// Workspace layout (floats)
#define OFF_XSRC 0                        // B*S*16 = 524288
#define OFF_Q    524288                   // B*H*S*4 = 524288
#define OFF_K    1048576
#define OFF_V    1572864
#define OFF_H1   2097152                  // B*8*S  = 262144 -> ends 2359296
#define OFF_H2   2359296                  // B*32*S = 1048576 -> ends 3407872
#define OFF_GDW  3407872                  // B*16*S = 524288 -> ends 3932160
#define OFF_PART 3932160                  // attn partials

// fp32 -> bf16 (RNE)
__device__ __forceinline__ short f2bf(float f) {
    union { float f; unsigned u; } a; a.f = f;
    unsigned r = (a.u + 0x7FFF + ((a.u >> 16) & 1)) >> 16;
    return (short)r;
}
// pack two fp32 -> bf16x2 (RNE)
__device__ __forceinline__ unsigned pk2bf(float a, float b) {
    union { __hip_bfloat162 h; unsigned u; } c;
    c.h = __float22bfloat162_rn(make_float2(a, b));
    return c.u;
}

// PE row (inline): pe[2j]=sin(ang), pe[2j+1]=cos(ang)
__device__ __forceinline__ void pe_row(int s, float* p) {
    #pragma unroll
    for (int j = 0; j < 8; j++) {
        float div = EXP2((float)j * -1.66096404744f);   // 10000^(-j/8)
        float ang = (float)s * div * (16.f / 1024.f);
        p[2*j]   = __sinf(ang);
        p[2*j+1] = __cosf(ang);
    }
}

// 16->16 projection to one of q/k/v: dst[(b*H+h)*S*4 + s*4 + d] = W[4h+d,:].t
__device__ __forceinline__ void proj16(const float* t, const float* __restrict__ W,
                                       float* __restrict__ dst, int b, int s) {
    #pragma unroll
    for (int h = 0; h < 4; h++) {
        float4 r;
        #pragma unroll
        for (int d = 0; d < 4; d++) {
            int e = h * 4 + d;
            float acc = 0.f;
            #pragma unroll
            for (int f = 0; f < 16; f++) acc += W[e * 16 + f] * t[f];
            ((float*)&r)[d] = acc;
        }
        ((float4*)(dst + ((size_t)(b * HH + h) * SS + s) * 4))[0] = r;
    }
}

// conv1: Conv1d(1->8,k8,s4) + BN + ReLU
__global__ __launch_bounds__(256) void conv1_kernel(const float* __restrict__ x,
        const float* __restrict__ w, const float* __restrict__ bias,
        const float* __restrict__ g, const float* __restrict__ bb,
        float* __restrict__ h1) {
    int idx = blockIdx.x * 256 + threadIdx.x;       // B*8*S
    int s = idx & 1023; int c = (idx >> 10) & 7; int b = idx >> 13;
    const float* xp = x + b * LL + 4 * s;
    float acc = bias[c];
    #pragma unroll
    for (int k = 0; k < 8; k++) acc += xp[k] * w[c * 8 + k];
    float inv = rsqrtf(1.f + 1e-5f);
    float v = acc * inv * g[c] + bb[c];
    h1[idx] = fmaxf(v, 0.f);
}

// conv2: Conv1d(8->32,k8,same) + BN + ReLU
__global__ __launch_bounds__(256) void conv2_kernel(const float* __restrict__ h1,
        const float* __restrict__ w, const float* __restrict__ bias,
        const float* __restrict__ g, const float* __restrict__ bb,
        float* __restrict__ h2) {
    int s = blockIdx.x * 256 + threadIdx.x;
    int o = blockIdx.y, b = blockIdx.z;
    const float* hp = h1 + b * 8 * SS;
    float acc = bias[o];
    #pragma unroll
    for (int i = 0; i < 8; i++) {
        const float* row = hp + i * SS;
        const float* wr = w + (o * 8 + i) * 8;
        #pragma unroll
        for (int k = 0; k < 8; k++) {
            int t = s - 3 + k;
            if (t >= 0 && t < SS) acc += row[t] * wr[k];
        }
    }
    float inv = rsqrtf(1.f + 1e-5f);
    float v = acc * inv * g[o] + bb[o];
    h2[(b * 32 + o) * SS + s] = fmaxf(v, 0.f);
}

// dw: grouped depthwise conv (32->16,k32,same,g16)
__global__ __launch_bounds__(256) void dw_kernel(const float* __restrict__ h2,
        const float* __restrict__ dw, float* __restrict__ gdw) {
    int s = blockIdx.x * 256 + threadIdx.x;
    int o = blockIdx.y, b = blockIdx.z;
    const float* r0 = h2 + (size_t)(b * 32 + 2 * o) * SS;
    const float* r1 = r0 + SS;
    const float* w0 = dw + (o * 2) * 32;   // uniform -> scalar loads
    const float* w1 = w0 + 32;
    float acc = 0.f;
    #pragma unroll
    for (int kk = 0; kk < 32; kk++) {
        int t = s - 15 + kk;
        if (t >= 0 && t < SS) acc += r0[t] * w0[kk] + r1[t] * w1[kk];
    }
    gdw[(size_t)(b * 16 + o) * SS + s] = acc;
}

// pw + layer-1 QKV, 3-way split (blockIdx.y = which of q/k/v), PE inline.
__global__ __launch_bounds__(256) void pw_qkv(const float* __restrict__ gdw,
        const float* __restrict__ pwm, const float* __restrict__ g3,
        const float* __restrict__ b3,
        const float* __restrict__ wq, const float* __restrict__ wk,
        const float* __restrict__ wv,
        float* __restrict__ xsrc,
        float* __restrict__ q, float* __restrict__ k, float* __restrict__ v) {
    int tid = threadIdx.x;
    int which = blockIdx.y;
    const float* wsel = (which == 0) ? wq : (which == 1) ? wk : wv;
    float* osel = (which == 0) ? q : (which == 1) ? k : v;
    int idx = blockIdx.x * 256 + tid;               // b*S + s
    int s = idx & 1023, b = idx >> 10;
    float gout[16];
    #pragma unroll
    for (int o = 0; o < 16; o++) gout[o] = gdw[(size_t)(b * 16 + o) * SS + s];
    const float inv = rsqrtf(1.f + 1e-5f);
    float t[16], p[16];
    pe_row(s, p);
    float* xp = xsrc + (size_t)idx * 16;
    #pragma unroll
    for (int pq = 0; pq < 16; pq++) {
        float acc = 0.f;
        #pragma unroll
        for (int o = 0; o < 16; o++) acc += pwm[pq * 16 + o] * gout[o];
        float xv = fmaxf(acc * inv * g3[pq] + b3[pq], 0.f);
        if (which == 0) xp[pq] = xv;
        t[pq] = xv + p[pq];
    }
    proj16(t, wsel, osel, b, s);
}

// MFMA flash attention (R11-proven: single s-tile/wave + chunk prefetch).
// Block = (bh, s-block of 64, t-chunk of TC); 4 waves, wave owns one 16-s tile.
// Per 32-t chunk: 2x S-MFMA (16x16x32 bf16), exp2(d*|t-s|) with folded scale,
// bf16 P via wave-private LDS, PV MFMA with V^T in LDS (row 4 = ones -> l).
template <int TC>
__global__ __launch_bounds__(256) void attn_mfma(const float* __restrict__ q,
        const float* __restrict__ k, const float* __restrict__ v,
        float* __restrict__ partO, float* __restrict__ partL) {
    constexpr int NCH = TC / 32;
    __shared__ __align__(16) short Ksh[TC * 4];          // [t][d] bf16
    __shared__ __align__(16) short Vtsh[16][TC + 8];     // [n][t] bf16
    __shared__ __align__(16) unsigned Psh[4][16 * 20];   // per-wave P tile
    int bh = blockIdx.x, sblk = blockIdx.y, tc = blockIdx.z;
    int tid = threadIdx.x;
    int wave = tid >> 6, lane = tid & 63;
    int col = lane & 15, quad = lane >> 4;
    int t0 = tc * TC;

    const float4* kg = (const float4*)(k + (size_t)bh * SS * 4) + t0;
    const float4* vg = (const float4*)(v + (size_t)bh * SS * 4) + t0;
    for (int t = tid; t < TC; t += 256) {
        float4 kk = kg[t];
        Ksh[t * 4 + 0] = f2bf(kk.x); Ksh[t * 4 + 1] = f2bf(kk.y);
        Ksh[t * 4 + 2] = f2bf(kk.z); Ksh[t * 4 + 3] = f2bf(kk.w);
        float4 vv = vg[t];
        Vtsh[0][t] = f2bf(vv.x); Vtsh[1][t] = f2bf(vv.y);
        Vtsh[2][t] = f2bf(vv.z); Vtsh[3][t] = f2bf(vv.w);
        Vtsh[4][t] = (short)0x3F80;                      // ones row -> l = sum(p)
        #pragma unroll
        for (int n = 5; n < 16; n++) Vtsh[n][t] = 0;
    }
    __syncthreads();

    int s0 = sblk * 64 + wave * 16;
    int sg = s0 + col;
    short8v bq = {0, 0, 0, 0, 0, 0, 0, 0};
    {
        const float cfold = 1.44269504089f / 4096.f;     // log2(e) * scale/n
        float4 qq = ((const float4*)(q + (size_t)bh * SS * 4))[sg];
        if (quad == 0) {
            bq[0] = f2bf(qq.x * cfold); bq[1] = f2bf(qq.y * cfold);
            bq[2] = f2bf(qq.z * cfold); bq[3] = f2bf(qq.w * cfold);
        }
    }
    float tf[8];
    #pragma unroll
    for (int r = 0; r < 8; r++)
        tf[r] = (float)(t0 + (r >> 2) * 16 + quad * 4 + (r & 3) - sg);
    float4v acc = {0.f, 0.f, 0.f, 0.f};
    unsigned* Pw = Psh[wave];
    // prefetch chunk 0 operands
    short8v a0 = {0,0,0,0,0,0,0,0}, a1 = {0,0,0,0,0,0,0,0};
    if (quad == 0) {
        int tb = col * 4;
        a0[0]=Ksh[tb+0]; a0[1]=Ksh[tb+1]; a0[2]=Ksh[tb+2]; a0[3]=Ksh[tb+3];
        a1[0]=Ksh[tb+64]; a1[1]=Ksh[tb+65]; a1[2]=Ksh[tb+66]; a1[3]=Ksh[tb+67];
    }
    short8v av = *((const short8v*)&Vtsh[col][quad * 8]);
    for (int ch = 0; ch < NCH; ch++) {
        float4v z = {0.f, 0.f, 0.f, 0.f};
        float4v c0 = __builtin_amdgcn_mfma_f32_16x16x32_bf16(a0, bq, z, 0, 0, 0);
        float4v c1 = __builtin_amdgcn_mfma_f32_16x16x32_bf16(a1, bq, z, 0, 0, 0);
        // prefetch next chunk while MFMA results land
        short8v a0n = {0,0,0,0,0,0,0,0}, a1n = {0,0,0,0,0,0,0,0}, avn = {0,0,0,0,0,0,0,0};
        if (ch + 1 < NCH) {
            if (quad == 0) {
                int tb = ((ch + 1) * 32 + col) * 4;
                a0n[0]=Ksh[tb+0]; a0n[1]=Ksh[tb+1]; a0n[2]=Ksh[tb+2]; a0n[3]=Ksh[tb+3];
                a1n[0]=Ksh[tb+64]; a1n[1]=Ksh[tb+65]; a1n[2]=Ksh[tb+66]; a1n[3]=Ksh[tb+67];
            }
            avn = *((const short8v*)&Vtsh[col][(ch + 1) * 32 + quad * 8]);
        }
        float p[8];
        #pragma unroll
        for (int r = 0; r < 4; r++) {
            p[r]     = EXP2(c0[r] * fabsf(tf[r]));     tf[r] += 32.f;
            p[4 + r] = EXP2(c1[r] * fabsf(tf[4 + r])); tf[4 + r] += 32.f;
        }
        unsigned base = col * 20 + quad * 2;
        Pw[base + 0] = pk2bf(p[0], p[1]);
        Pw[base + 1] = pk2bf(p[2], p[3]);
        Pw[base + 8] = pk2bf(p[4], p[5]);
        Pw[base + 9] = pk2bf(p[6], p[7]);
        short8v pb = *((const short8v*)&Pw[col * 20 + quad * 4]);
        acc = __builtin_amdgcn_mfma_f32_16x16x32_bf16(av, pb, acc, 0, 0, 0);
        a0 = a0n; a1 = a1n; av = avn;
    }
    size_t o = (size_t)(tc * (BB * HH) + bh) * SS + sg;
    if (quad == 0) {
        float4 r; r.x = acc[0]; r.y = acc[1]; r.z = acc[2]; r.w = acc[3];
        ((float4*)partO)[o] = r;
    } else if (quad == 1) {
        partL[o] = acc[0];                                // ones column = sum(p)
    }
}

// Layer-1 epilogue fused with layer-2 QKV, 3-way split, PE inline.
__global__ __launch_bounds__(256) void post_qkv(const float* __restrict__ partO,
        const float* __restrict__ partL, int nsplit,
        const float* __restrict__ res,
        const float* __restrict__ lnag, const float* __restrict__ lnab,
        const float* __restrict__ lng, const float* __restrict__ lnb,
        const float* __restrict__ wq, const float* __restrict__ wk,
        const float* __restrict__ wv,
        float* __restrict__ q, float* __restrict__ k, float* __restrict__ v) {
    int tid = threadIdx.x;
    int which = blockIdx.y;
    const float* wsel = (which == 0) ? wq : (which == 1) ? wk : wv;
    float* osel = (which == 0) ? q : (which == 1) ? k : v;
    int idx = blockIdx.x * 256 + tid;               // b*S + s
    int s = idx & 1023, b = idx >> 10;
    float t[16];
    #pragma unroll
    for (int h = 0; h < HH; h++) {
        int bh = b * HH + h;
        float ox = 0.f, oy = 0.f, oz = 0.f, ow = 0.f, l = 0.f;
        for (int c = 0; c < nsplit; c++) {
            size_t o = (size_t)(c * (BB * HH) + bh) * SS + s;
            float4 O = ((const float4*)partO)[o];
            ox += O.x; oy += O.y; oz += O.z; ow += O.w;
            l += partL[o];
        }
        float rl = 1.f / l;
        t[h*4+0] = ox * rl; t[h*4+1] = oy * rl;
        t[h*4+2] = oz * rl; t[h*4+3] = ow * rl;
    }
    float mu = 0.f;
    #pragma unroll
    for (int e = 0; e < 16; e++) mu += t[e];
    mu *= (1.f / 16.f);
    float var = 0.f;
    #pragma unroll
    for (int e = 0; e < 16; e++) { float d = t[e] - mu; var += d * d; }
    var *= (1.f / 16.f);
    float r = rsqrtf(var + 1e-5f);
    const float4* rp = (const float4*)(res + ((size_t)b * SS + s) * 16);
    #pragma unroll
    for (int i = 0; i < 4; i++) {
        float4 a = rp[i];
        t[4*i+0] = (t[4*i+0]-mu)*r*lnag[4*i+0] + lnab[4*i+0] + a.x;
        t[4*i+1] = (t[4*i+1]-mu)*r*lnag[4*i+1] + lnab[4*i+1] + a.y;
        t[4*i+2] = (t[4*i+2]-mu)*r*lnag[4*i+2] + lnab[4*i+2] + a.z;
        t[4*i+3] = (t[4*i+3]-mu)*r*lnag[4*i+3] + lnab[4*i+3] + a.w;
    }
    float mu2 = 0.f;
    #pragma unroll
    for (int e = 0; e < 16; e++) mu2 += t[e];
    mu2 *= (1.f / 16.f);
    float var2 = 0.f;
    #pragma unroll
    for (int e = 0; e < 16; e++) { float d = t[e] - mu2; var2 += d * d; }
    var2 *= (1.f / 16.f);
    float r2 = rsqrtf(var2 + 1e-5f);
    float p[16];
    pe_row(s, p);
    #pragma unroll
    for (int e = 0; e < 16; e++)
        t[e] = (t[e]-mu2)*r2*lng[e] + lnb[e] + p[e];
    proj16(t, wsel, osel, b, s);
}

// Layer-2 epilogue + pool + final linear, one block per b.
__global__ __launch_bounds__(256) void post_pool(const float* __restrict__ partO,
        const float* __restrict__ partL, int nsplit,
        const float* __restrict__ lnag, const float* __restrict__ lnab,
        const float* __restrict__ lng, const float* __restrict__ lnb,
        const float* __restrict__ ow, const float* __restrict__ ob,
        float* __restrict__ out) {
    __shared__ float red[256 * 17];
    int tid = threadIdx.x;
    int b = blockIdx.x;
    float acc16[16];
    #pragma unroll
    for (int e = 0; e < 16; e++) acc16[e] = 0.f;
    for (int c4 = 0; c4 < 4; c4++) {
        int s = c4 * 256 + tid;
        float t[16];
        #pragma unroll
        for (int h = 0; h < HH; h++) {
            int bh = b * HH + h;
            float ox = 0.f, oy = 0.f, oz = 0.f, owv = 0.f, l = 0.f;
            for (int c = 0; c < nsplit; c++) {
                size_t o = (size_t)(c * (BB * HH) + bh) * SS + s;
                float4 O = ((const float4*)partO)[o];
                ox += O.x; oy += O.y; oz += O.z; owv += O.w;
                l += partL[o];
            }
            float rl = 1.f / l;
            t[h*4+0] = ox * rl; t[h*4+1] = oy * rl;
            t[h*4+2] = oz * rl; t[h*4+3] = owv * rl;
        }
        float mu = 0.f;
        #pragma unroll
        for (int e = 0; e < 16; e++) mu += t[e];
        mu *= (1.f / 16.f);
        float var = 0.f;
        #pragma unroll
        for (int e = 0; e < 16; e++) { float d = t[e] - mu; var += d * d; }
        var *= (1.f / 16.f);
        float r = rsqrtf(var + 1e-5f);
        #pragma unroll
        for (int e = 0; e < 16; e++) t[e] = (t[e]-mu)*r*lnag[e] + lnab[e];
        float mu2 = 0.f;
        #pragma unroll
        for (int e = 0; e < 16; e++) mu2 += t[e];
        mu2 *= (1.f / 16.f);
        float var2 = 0.f;
        #pragma unroll
        for (int e = 0; e < 16; e++) { float d = t[e] - mu2; var2 += d * d; }
        var2 *= (1.f / 16.f);
        float r2 = rsqrtf(var2 + 1e-5f);
        #pragma unroll
        for (int e = 0; e < 16; e++)
            acc16[e] += (t[e]-mu2)*r2*lng[e] + lnb[e];
    }
    #pragma unroll
    for (int e = 0; e < 16; e++) red[tid * 17 + e] = acc16[e];
    __syncthreads();
    for (int off = 128; off > 0; off >>= 1) {
        if (tid < off) {
            #pragma unroll
            for (int e = 0; e < 16; e++) red[tid * 17 + e] += red[(tid + off) * 17 + e];
        }
        __syncthreads();
    }
    if (tid < NCC) {
        float a = ob[tid];
        #pragma unroll
        for (int e = 0; e < 16; e++)
            a += (red[e] * (1.f / 1024.f)) * ow[tid * 16 + e];
        out[b * NCC + tid] = a;
    }
}

extern "C" void kernel_launch(void* const* d_in, const int* in_sizes, int n_in,
                              void* d_out, int out_size, void* d_ws, size_t ws_size,
                              hipStream_t stream) {
    const float* x       = (const float*)d_in[0];
    const float* patch_w = (const float*)d_in[1];
    const float* patch_b = (const float*)d_in[2];
    const float* bn1_g   = (const float*)d_in[3];
    const float* bn1_b   = (const float*)d_in[4];
    const float* emb_w   = (const float*)d_in[5];
    const float* emb_b   = (const float*)d_in[6];
    const float* bn2_g   = (const float*)d_in[7];
    const float* bn2_b   = (const float*)d_in[8];
    const float* dw_w    = (const float*)d_in[9];
    const float* pw_w    = (const float*)d_in[10];
    const float* bn3_g   = (const float*)d_in[11];
    const float* bn3_b   = (const float*)d_in[12];
    const float* q1_w    = (const float*)d_in[13];
    const float* k1_w    = (const float*)d_in[14];
    const float* v1_w    = (const float*)d_in[15];
    const float* lna1_g  = (const float*)d_in[16];
    const float* lna1_b  = (const float*)d_in[17];
    const float* ln1_g   = (const float*)d_in[18];
    const float* ln1_b   = (const float*)d_in[19];
    const float* q2_w    = (const float*)d_in[20];
    const float* k2_w    = (const float*)d_in[21];
    const float* v2_w    = (const float*)d_in[22];
    const float* lna2_g  = (const float*)d_in[23];
    const float* lna2_b  = (const float*)d_in[24];
    const float* ln2_g   = (const float*)d_in[25];
    const float* ln2_b   = (const float*)d_in[26];
    const float* out_w   = (const float*)d_in[27];
    const float* out_b   = (const float*)d_in[28];

    float* ws    = (float*)d_ws;
    float* xsrc  = ws + OFF_XSRC;
    float* q     = ws + OFF_Q;
    float* k     = ws + OFF_K;
    float* v     = ws + OFF_V;
    float* h1    = ws + OFF_H1;
    float* h2    = ws + OFF_H2;
    float* gdw   = ws + OFF_GDW;
    float* out   = (float*)d_out;

    // attn t-split: 4-way (TC=256) if workspace allows, else 2-way (TC=512)
    int tsplit; float *partO, *partL;
    size_t need4 = (size_t)(OFF_PART + 4 * 131072 * 5) * 4;
    if (ws_size >= need4) {
        tsplit = 4;
        partO = ws + OFF_PART;
        partL = ws + OFF_PART + 4 * 131072 * 4;
    } else {
        tsplit = 2;
        partO = ws + OFF_PART;
        partL = ws + OFF_PART + 2 * 131072 * 4;
    }

    conv1_kernel<<<1024, 256, 0, stream>>>(x, patch_w, patch_b, bn1_g, bn1_b, h1);
    conv2_kernel<<<dim3(4, 32, BB), 256, 0, stream>>>(h1, emb_w, emb_b, bn2_g, bn2_b, h2);
    dw_kernel<<<dim3(4, 16, BB), 256, 0, stream>>>(h2, dw_w, gdw);
    pw_qkv<<<dim3(128, 3), 256, 0, stream>>>(gdw, pw_w, bn3_g, bn3_b,
        q1_w, k1_w, v1_w, xsrc, q, k, v);

    dim3 agrid(BB * HH, 16, tsplit);
    if (tsplit == 4) attn_mfma<256><<<agrid, 256, 0, stream>>>(q, k, v, partO, partL);
    else             attn_mfma<512><<<agrid, 256, 0, stream>>>(q, k, v, partO, partL);

    post_qkv<<<dim3(128, 3), 256, 0, stream>>>(partO, partL, tsplit, xsrc,
        lna1_g, lna1_b, ln1_g, ln1_b, q2_w, k2_w, v2_w, q, k, v);

    if (tsplit == 4) attn_mfma<256><<<agrid, 256, 0, stream>>>(q, k, v, partO, partL);
    else             attn_mfma<512><<<agrid, 256, 0, stream>>>(q, k, v, partO, partL);

    post_pool<<<BB, 256, 0, stream>>>(partO, partL, tsplit,
        lna2_g, lna2_b, ln2_g, ln2_b, out_w, out_b, out);
}

// Round 14
// 252.069 us; speedup vs baseline: 1.0483x; 1.0483x over previous
//
#include <hip/hip_runtime.h>
#include <hip/hip_bf16.h>
#include <math.h>

// Problem constants
#define BB 32
#define LL 4100
#define SS 1024
#define EE 16
#define HH 4
#define DHD 4
#define NCC 10

// Native exp2: single v_exp_f32; libm exp2f lowers to ~30-inst OCML (R6 finding).
#define EXP2(x) __builtin_amdgcn_exp2f(x)

typedef __attribute__((ext_vector_type(8))) short short8v;   // 8 bf16 = 4 VGPR (MFMA A/B)
typedef __attribute__((ext_vector_type(4))) float float4v;   // MFMA C/D

// Workspace layout (floats)
#define OFF_XSRC 0                        // B*S*16 = 524288
#define OFF_Q    524288                   // B*H*S*4 = 524288
#define OFF_K    1048576
#define OFF_V    1572864
#define OFF_PE   2097152                  // S*16 = 16384 -> ends 2113536
#define OFF_POOLP 2113536                 // BB*4*16 = 2048 -> ends 2115584
#define OFF_H1   2115584                  // B*8*S  = 262144 -> ends 2377728
#define OFF_H2   2377728                  // B*32*S = 1048576 -> ends 3426304
#define OFF_GDW  3426304                  // B*16*S = 524288 -> ends 3950592
#define OFF_PART 3950592                  // attn partials

// fp32 -> bf16 (RNE)
__device__ __forceinline__ short f2bf(float f) {
    union { float f; unsigned u; } a; a.f = f;
    unsigned r = (a.u + 0x7FFF + ((a.u >> 16) & 1)) >> 16;
    return (short)r;
}
// pack two fp32 -> bf16x2 (RNE)
__device__ __forceinline__ unsigned pk2bf(float a, float b) {
    union { __hip_bfloat162 h; unsigned u; } c;
    c.h = __float22bfloat162_rn(make_float2(a, b));
    return c.u;
}

// 16->16 projection to one of q/k/v: dst[(b*H+h)*S*4 + s*4 + d] = W[4h+d,:].t
__device__ __forceinline__ void proj16(const float* t, const float* __restrict__ W,
                                       float* __restrict__ dst, int b, int s) {
    #pragma unroll
    for (int h = 0; h < 4; h++) {
        float4 r;
        #pragma unroll
        for (int d = 0; d < 4; d++) {
            int e = h * 4 + d;
            float acc = 0.f;
            #pragma unroll
            for (int f = 0; f < 16; f++) acc += W[e * 16 + f] * t[f];
            ((float*)&r)[d] = acc;
        }
        ((float4*)(dst + ((size_t)(b * HH + h) * SS + s) * 4))[0] = r;
    }
}

// PE table: pe[s][2j]=sin(ang), pe[s][2j+1]=cos(ang)
__global__ __launch_bounds__(256) void pe_kernel(float* pe) {
    int idx = blockIdx.x * 256 + threadIdx.x;       // S*E = 16384
    int s = idx >> 4, e = idx & 15;
    int j = e >> 1;
    float div = EXP2((float)j * -1.66096404744f);   // 10000^(-j/8)
    float ang = (float)s * div * (16.f / 1024.f);
    pe[idx] = (e & 1) ? __cosf(ang) : __sinf(ang);
}

// conv1: Conv1d(1->8,k8,s4) + BN + ReLU
__global__ __launch_bounds__(256) void conv1_kernel(const float* __restrict__ x,
        const float* __restrict__ w, const float* __restrict__ bias,
        const float* __restrict__ g, const float* __restrict__ bb,
        float* __restrict__ h1) {
    int idx = blockIdx.x * 256 + threadIdx.x;       // B*8*S
    int s = idx & 1023; int c = (idx >> 10) & 7; int b = idx >> 13;
    const float* xp = x + b * LL + 4 * s;
    float acc = bias[c];
    #pragma unroll
    for (int k = 0; k < 8; k++) acc += xp[k] * w[c * 8 + k];
    float inv = rsqrtf(1.f + 1e-5f);
    float v = acc * inv * g[c] + bb[c];
    h1[idx] = fmaxf(v, 0.f);
}

// conv2: Conv1d(8->32,k8,same) + BN + ReLU
__global__ __launch_bounds__(256) void conv2_kernel(const float* __restrict__ h1,
        const float* __restrict__ w, const float* __restrict__ bias,
        const float* __restrict__ g, const float* __restrict__ bb,
        float* __restrict__ h2) {
    int s = blockIdx.x * 256 + threadIdx.x;
    int o = blockIdx.y, b = blockIdx.z;
    const float* hp = h1 + b * 8 * SS;
    float acc = bias[o];
    #pragma unroll
    for (int i = 0; i < 8; i++) {
        const float* row = hp + i * SS;
        const float* wr = w + (o * 8 + i) * 8;
        #pragma unroll
        for (int k = 0; k < 8; k++) {
            int t = s - 3 + k;
            if (t >= 0 && t < SS) acc += row[t] * wr[k];
        }
    }
    float inv = rsqrtf(1.f + 1e-5f);
    float v = acc * inv * g[o] + bb[o];
    h2[(b * 32 + o) * SS + s] = fmaxf(v, 0.f);
}

// dw: grouped depthwise conv (32->16,k32,same,g16)
__global__ __launch_bounds__(256) void dw_kernel(const float* __restrict__ h2,
        const float* __restrict__ dw, float* __restrict__ gdw) {
    int s = blockIdx.x * 256 + threadIdx.x;
    int o = blockIdx.y, b = blockIdx.z;
    const float* r0 = h2 + (size_t)(b * 32 + 2 * o) * SS;
    const float* r1 = r0 + SS;
    const float* w0 = dw + (o * 2) * 32;   // uniform -> scalar loads
    const float* w1 = w0 + 32;
    float acc = 0.f;
    #pragma unroll
    for (int kk = 0; kk < 32; kk++) {
        int t = s - 15 + kk;
        if (t >= 0 && t < SS) acc += r0[t] * w0[kk] + r1[t] * w1[kk];
    }
    gdw[(size_t)(b * 16 + o) * SS + s] = acc;
}

// pw + layer-1 QKV, 3-way split (blockIdx.y = which of q/k/v).
// Each replica recomputes the cheap pw+BN+ReLU; replica 0 also writes xsrc.
__global__ __launch_bounds__(256) void pw_qkv(const float* __restrict__ gdw,
        const float* __restrict__ pwm, const float* __restrict__ g3,
        const float* __restrict__ b3, const float* __restrict__ pe,
        const float* __restrict__ wq, const float* __restrict__ wk,
        const float* __restrict__ wv,
        float* __restrict__ xsrc,
        float* __restrict__ q, float* __restrict__ k, float* __restrict__ v) {
    int tid = threadIdx.x;
    int which = blockIdx.y;
    const float* wsel = (which == 0) ? wq : (which == 1) ? wk : wv;
    float* osel = (which == 0) ? q : (which == 1) ? k : v;
    int idx = blockIdx.x * 256 + tid;               // b*S + s
    int s = idx & 1023, b = idx >> 10;
    float gout[16];
    #pragma unroll
    for (int o = 0; o < 16; o++) gout[o] = gdw[(size_t)(b * 16 + o) * SS + s];
    const float inv = rsqrtf(1.f + 1e-5f);
    float t[16];
    const float4* pp = (const float4*)(pe + s * 16);
    float* xp = xsrc + (size_t)idx * 16;
    #pragma unroll
    for (int pq = 0; pq < 16; pq++) {
        float acc = 0.f;
        #pragma unroll
        for (int o = 0; o < 16; o++) acc += pwm[pq * 16 + o] * gout[o];
        float xv = fmaxf(acc * inv * g3[pq] + b3[pq], 0.f);
        if (which == 0) xp[pq] = xv;
        t[pq] = xv;
    }
    #pragma unroll
    for (int i = 0; i < 4; i++) {
        float4 p = pp[i];
        t[4*i+0] += p.x; t[4*i+1] += p.y; t[4*i+2] += p.z; t[4*i+3] += p.w;
    }
    proj16(t, wsel, osel, b, s);
}

// MFMA flash attention with chunk prefetch (R10 structure + pipelining).
template <int TC>
__global__ __launch_bounds__(256) void attn_mfma(const float* __restrict__ q,
        const float* __restrict__ k, const float* __restrict__ v,
        float* __restrict__ partO, float* __restrict__ partL) {
    constexpr int NCH = TC / 32;
    __shared__ __align__(16) short Ksh[TC * 4];          // [t][d] bf16
    __shared__ __align__(16) short Vtsh[16][TC + 8];     // [n][t] bf16
    __shared__ __align__(16) unsigned Psh[4][16 * 20];   // per-wave P tile
    int bh = blockIdx.x, sblk = blockIdx.y, tc = blockIdx.z;
    int tid = threadIdx.x;
    int wave = tid >> 6, lane = tid & 63;
    int col = lane & 15, quad = lane >> 4;
    int t0 = tc * TC;

    const float4* kg = (const float4*)(k + (size_t)bh * SS * 4) + t0;
    const float4* vg = (const float4*)(v + (size_t)bh * SS * 4) + t0;
    for (int t = tid; t < TC; t += 256) {
        float4 kk = kg[t];
        Ksh[t * 4 + 0] = f2bf(kk.x); Ksh[t * 4 + 1] = f2bf(kk.y);
        Ksh[t * 4 + 2] = f2bf(kk.z); Ksh[t * 4 + 3] = f2bf(kk.w);
        float4 vv = vg[t];
        Vtsh[0][t] = f2bf(vv.x); Vtsh[1][t] = f2bf(vv.y);
        Vtsh[2][t] = f2bf(vv.z); Vtsh[3][t] = f2bf(vv.w);
        Vtsh[4][t] = (short)0x3F80;                      // ones row -> l = sum(p)
        #pragma unroll
        for (int n = 5; n < 16; n++) Vtsh[n][t] = 0;
    }
    __syncthreads();

    int s0 = sblk * 64 + wave * 16;
    int sg = s0 + col;
    short8v bq = {0, 0, 0, 0, 0, 0, 0, 0};
    {
        const float cfold = 1.44269504089f / 4096.f;     // log2(e) * scale/n
        float4 qq = ((const float4*)(q + (size_t)bh * SS * 4))[sg];
        if (quad == 0) {
            bq[0] = f2bf(qq.x * cfold); bq[1] = f2bf(qq.y * cfold);
            bq[2] = f2bf(qq.z * cfold); bq[3] = f2bf(qq.w * cfold);
        }
    }
    float tf[8];
    #pragma unroll
    for (int r = 0; r < 8; r++)
        tf[r] = (float)(t0 + (r >> 2) * 16 + quad * 4 + (r & 3) - sg);
    float4v acc = {0.f, 0.f, 0.f, 0.f};
    unsigned* Pw = Psh[wave];
    // prefetch chunk 0 operands
    short8v a0 = {0,0,0,0,0,0,0,0}, a1 = {0,0,0,0,0,0,0,0};
    if (quad == 0) {
        int tb = col * 4;
        a0[0]=Ksh[tb+0]; a0[1]=Ksh[tb+1]; a0[2]=Ksh[tb+2]; a0[3]=Ksh[tb+3];
        a1[0]=Ksh[tb+64]; a1[1]=Ksh[tb+65]; a1[2]=Ksh[tb+66]; a1[3]=Ksh[tb+67];
    }
    short8v av = *((const short8v*)&Vtsh[col][quad * 8]);
    for (int ch = 0; ch < NCH; ch++) {
        float4v z = {0.f, 0.f, 0.f, 0.f};
        float4v c0 = __builtin_amdgcn_mfma_f32_16x16x32_bf16(a0, bq, z, 0, 0, 0);
        float4v c1 = __builtin_amdgcn_mfma_f32_16x16x32_bf16(a1, bq, z, 0, 0, 0);
        // prefetch next chunk while MFMA results land
        short8v a0n = {0,0,0,0,0,0,0,0}, a1n = {0,0,0,0,0,0,0,0}, avn = {0,0,0,0,0,0,0,0};
        if (ch + 1 < NCH) {
            if (quad == 0) {
                int tb = ((ch + 1) * 32 + col) * 4;
                a0n[0]=Ksh[tb+0]; a0n[1]=Ksh[tb+1]; a0n[2]=Ksh[tb+2]; a0n[3]=Ksh[tb+3];
                a1n[0]=Ksh[tb+64]; a1n[1]=Ksh[tb+65]; a1n[2]=Ksh[tb+66]; a1n[3]=Ksh[tb+67];
            }
            avn = *((const short8v*)&Vtsh[col][(ch + 1) * 32 + quad * 8]);
        }
        float p[8];
        #pragma unroll
        for (int r = 0; r < 4; r++) {
            p[r]     = EXP2(c0[r] * fabsf(tf[r]));     tf[r] += 32.f;
            p[4 + r] = EXP2(c1[r] * fabsf(tf[4 + r])); tf[4 + r] += 32.f;
        }
        unsigned base = col * 20 + quad * 2;
        Pw[base + 0] = pk2bf(p[0], p[1]);
        Pw[base + 1] = pk2bf(p[2], p[3]);
        Pw[base + 8] = pk2bf(p[4], p[5]);
        Pw[base + 9] = pk2bf(p[6], p[7]);
        short8v pb = *((const short8v*)&Pw[col * 20 + quad * 4]);
        acc = __builtin_amdgcn_mfma_f32_16x16x32_bf16(av, pb, acc, 0, 0, 0);
        a0 = a0n; a1 = a1n; av = avn;
    }
    size_t o = (size_t)(tc * (BB * HH) + bh) * SS + sg;
    if (quad == 0) {
        float4 r; r.x = acc[0]; r.y = acc[1]; r.z = acc[2]; r.w = acc[3];
        ((float4*)partO)[o] = r;
    } else if (quad == 1) {
        partL[o] = acc[0];                                // ones column = sum(p)
    }
}

// Layer-1 epilogue fused with layer-2 QKV, 3-way split (blockIdx.y = q/k/v).
__global__ __launch_bounds__(256) void post_qkv(const float* __restrict__ partO,
        const float* __restrict__ partL, int nsplit,
        const float* __restrict__ res, const float* __restrict__ pe,
        const float* __restrict__ lnag, const float* __restrict__ lnab,
        const float* __restrict__ lng, const float* __restrict__ lnb,
        const float* __restrict__ wq, const float* __restrict__ wk,
        const float* __restrict__ wv,
        float* __restrict__ q, float* __restrict__ k, float* __restrict__ v) {
    int tid = threadIdx.x;
    int which = blockIdx.y;
    const float* wsel = (which == 0) ? wq : (which == 1) ? wk : wv;
    float* osel = (which == 0) ? q : (which == 1) ? k : v;
    int idx = blockIdx.x * 256 + tid;               // b*S + s
    int s = idx & 1023, b = idx >> 10;
    float t[16];
    #pragma unroll
    for (int h = 0; h < HH; h++) {
        int bh = b * HH + h;
        float ox = 0.f, oy = 0.f, oz = 0.f, ow = 0.f, l = 0.f;
        for (int c = 0; c < nsplit; c++) {
            size_t o = (size_t)(c * (BB * HH) + bh) * SS + s;
            float4 O = ((const float4*)partO)[o];
            ox += O.x; oy += O.y; oz += O.z; ow += O.w;
            l += partL[o];
        }
        float rl = 1.f / l;
        t[h*4+0] = ox * rl; t[h*4+1] = oy * rl;
        t[h*4+2] = oz * rl; t[h*4+3] = ow * rl;
    }
    float mu = 0.f;
    #pragma unroll
    for (int e = 0; e < 16; e++) mu += t[e];
    mu *= (1.f / 16.f);
    float var = 0.f;
    #pragma unroll
    for (int e = 0; e < 16; e++) { float d = t[e] - mu; var += d * d; }
    var *= (1.f / 16.f);
    float r = rsqrtf(var + 1e-5f);
    const float4* rp = (const float4*)(res + ((size_t)b * SS + s) * 16);
    #pragma unroll
    for (int i = 0; i < 4; i++) {
        float4 a = rp[i];
        t[4*i+0] = (t[4*i+0]-mu)*r*lnag[4*i+0] + lnab[4*i+0] + a.x;
        t[4*i+1] = (t[4*i+1]-mu)*r*lnag[4*i+1] + lnab[4*i+1] + a.y;
        t[4*i+2] = (t[4*i+2]-mu)*r*lnag[4*i+2] + lnab[4*i+2] + a.z;
        t[4*i+3] = (t[4*i+3]-mu)*r*lnag[4*i+3] + lnab[4*i+3] + a.w;
    }
    float mu2 = 0.f;
    #pragma unroll
    for (int e = 0; e < 16; e++) mu2 += t[e];
    mu2 *= (1.f / 16.f);
    float var2 = 0.f;
    #pragma unroll
    for (int e = 0; e < 16; e++) { float d = t[e] - mu2; var2 += d * d; }
    var2 *= (1.f / 16.f);
    float r2 = rsqrtf(var2 + 1e-5f);
    const float4* pp = (const float4*)(pe + s * 16);
    #pragma unroll
    for (int i = 0; i < 4; i++) {
        float4 p = pp[i];
        t[4*i+0] = (t[4*i+0]-mu2)*r2*lng[4*i+0] + lnb[4*i+0] + p.x;
        t[4*i+1] = (t[4*i+1]-mu2)*r2*lng[4*i+1] + lnb[4*i+1] + p.y;
        t[4*i+2] = (t[4*i+2]-mu2)*r2*lng[4*i+2] + lnb[4*i+2] + p.z;
        t[4*i+3] = (t[4*i+3]-mu2)*r2*lng[4*i+3] + lnb[4*i+3] + p.w;
    }
    proj16(t, wsel, osel, b, s);
}

// Layer-2 epilogue fused with pool partials
__global__ __launch_bounds__(256) void post_pool(const float* __restrict__ partO,
        const float* __restrict__ partL, int nsplit,
        const float* __restrict__ lnag, const float* __restrict__ lnab,
        const float* __restrict__ lng, const float* __restrict__ lnb,
        float* __restrict__ poolp) {
    __shared__ float red[256 * 17];
    int tid = threadIdx.x;
    int s = blockIdx.x * 256 + tid;
    int b = blockIdx.y;
    float t[16];
    #pragma unroll
    for (int h = 0; h < HH; h++) {
        int bh = b * HH + h;
        float ox = 0.f, oy = 0.f, oz = 0.f, ow = 0.f, l = 0.f;
        for (int c = 0; c < nsplit; c++) {
            size_t o = (size_t)(c * (BB * HH) + bh) * SS + s;
            float4 O = ((const float4*)partO)[o];
            ox += O.x; oy += O.y; oz += O.z; ow += O.w;
            l += partL[o];
        }
        float rl = 1.f / l;
        t[h*4+0] = ox * rl; t[h*4+1] = oy * rl;
        t[h*4+2] = oz * rl; t[h*4+3] = ow * rl;
    }
    float mu = 0.f;
    #pragma unroll
    for (int e = 0; e < 16; e++) mu += t[e];
    mu *= (1.f / 16.f);
    float var = 0.f;
    #pragma unroll
    for (int e = 0; e < 16; e++) { float d = t[e] - mu; var += d * d; }
    var *= (1.f / 16.f);
    float r = rsqrtf(var + 1e-5f);
    #pragma unroll
    for (int e = 0; e < 16; e++) t[e] = (t[e]-mu)*r*lnag[e] + lnab[e];
    float mu2 = 0.f;
    #pragma unroll
    for (int e = 0; e < 16; e++) mu2 += t[e];
    mu2 *= (1.f / 16.f);
    float var2 = 0.f;
    #pragma unroll
    for (int e = 0; e < 16; e++) { float d = t[e] - mu2; var2 += d * d; }
    var2 *= (1.f / 16.f);
    float r2 = rsqrtf(var2 + 1e-5f);
    #pragma unroll
    for (int e = 0; e < 16; e++)
        red[tid * 17 + e] = (t[e]-mu2)*r2*lng[e] + lnb[e];
    __syncthreads();
    for (int off = 128; off > 0; off >>= 1) {
        if (tid < off) {
            #pragma unroll
            for (int e = 0; e < 16; e++) red[tid * 17 + e] += red[(tid + off) * 17 + e];
        }
        __syncthreads();
    }
    if (tid < 16) poolp[(b * 4 + blockIdx.x) * 16 + tid] = red[tid];
}

// Final: reduce 4 chunk-partials per b, mean over S, linear 16->10
__global__ __launch_bounds__(512) void final_kernel(const float* __restrict__ poolp,
        const float* __restrict__ ow, const float* __restrict__ ob,
        float* __restrict__ out) {
    int t = threadIdx.x;
    if (t < BB * NCC) {
        int b = t / NCC, c = t - b * NCC;
        float a = ob[c];
        #pragma unroll
        for (int e = 0; e < 16; e++) {
            float sum = poolp[(b*4+0)*16+e] + poolp[(b*4+1)*16+e]
                      + poolp[(b*4+2)*16+e] + poolp[(b*4+3)*16+e];
            a += (sum * (1.f / 1024.f)) * ow[c * 16 + e];
        }
        out[b * NCC + c] = a;
    }
}

extern "C" void kernel_launch(void* const* d_in, const int* in_sizes, int n_in,
                              void* d_out, int out_size, void* d_ws, size_t ws_size,
                              hipStream_t stream) {
    const float* x       = (const float*)d_in[0];
    const float* patch_w = (const float*)d_in[1];
    const float* patch_b = (const float*)d_in[2];
    const float* bn1_g   = (const float*)d_in[3];
    const float* bn1_b   = (const float*)d_in[4];
    const float* emb_w   = (const float*)d_in[5];
    const float* emb_b   = (const float*)d_in[6];
    const float* bn2_g   = (const float*)d_in[7];
    const float* bn2_b   = (const float*)d_in[8];
    const float* dw_w    = (const float*)d_in[9];
    const float* pw_w    = (const float*)d_in[10];
    const float* bn3_g   = (const float*)d_in[11];
    const float* bn3_b   = (const float*)d_in[12];
    const float* q1_w    = (const float*)d_in[13];
    const float* k1_w    = (const float*)d_in[14];
    const float* v1_w    = (const float*)d_in[15];
    const float* lna1_g  = (const float*)d_in[16];
    const float* lna1_b  = (const float*)d_in[17];
    const float* ln1_g   = (const float*)d_in[18];
    const float* ln1_b   = (const float*)d_in[19];
    const float* q2_w    = (const float*)d_in[20];
    const float* k2_w    = (const float*)d_in[21];
    const float* v2_w    = (const float*)d_in[22];
    const float* lna2_g  = (const float*)d_in[23];
    const float* lna2_b  = (const float*)d_in[24];
    const float* ln2_g   = (const float*)d_in[25];
    const float* ln2_b   = (const float*)d_in[26];
    const float* out_w   = (const float*)d_in[27];
    const float* out_b   = (const float*)d_in[28];

    float* ws    = (float*)d_ws;
    float* xsrc  = ws + OFF_XSRC;
    float* q     = ws + OFF_Q;
    float* k     = ws + OFF_K;
    float* v     = ws + OFF_V;
    float* pe    = ws + OFF_PE;
    float* poolp = ws + OFF_POOLP;
    float* h1    = ws + OFF_H1;
    float* h2    = ws + OFF_H2;
    float* gdw   = ws + OFF_GDW;
    float* out   = (float*)d_out;

    // attn t-split: 4-way (TC=256) if workspace allows, else 2-way (TC=512)
    int tsplit; float *partO, *partL;
    size_t need4 = (size_t)(OFF_PART + 4 * 131072 * 5) * 4;
    if (ws_size >= need4) {
        tsplit = 4;
        partO = ws + OFF_PART;
        partL = ws + OFF_PART + 4 * 131072 * 4;
    } else {
        tsplit = 2;
        partO = ws + OFF_PART;
        partL = ws + OFF_PART + 2 * 131072 * 4;
    }

    pe_kernel<<<64, 256, 0, stream>>>(pe);
    conv1_kernel<<<1024, 256, 0, stream>>>(x, patch_w, patch_b, bn1_g, bn1_b, h1);
    conv2_kernel<<<dim3(4, 32, BB), 256, 0, stream>>>(h1, emb_w, emb_b, bn2_g, bn2_b, h2);
    dw_kernel<<<dim3(4, 16, BB), 256, 0, stream>>>(h2, dw_w, gdw);
    pw_qkv<<<dim3(128, 3), 256, 0, stream>>>(gdw, pw_w, bn3_g, bn3_b, pe,
        q1_w, k1_w, v1_w, xsrc, q, k, v);

    dim3 agrid(BB * HH, 16, tsplit);
    if (tsplit == 4) attn_mfma<256><<<agrid, 256, 0, stream>>>(q, k, v, partO, partL);
    else             attn_mfma<512><<<agrid, 256, 0, stream>>>(q, k, v, partO, partL);

    post_qkv<<<dim3(128, 3), 256, 0, stream>>>(partO, partL, tsplit, xsrc, pe,
        lna1_g, lna1_b, ln1_g, ln1_b, q2_w, k2_w, v2_w, q, k, v);

    if (tsplit == 4) attn_mfma<256><<<agrid, 256, 0, stream>>>(q, k, v, partO, partL);
    else             attn_mfma<512><<<agrid, 256, 0, stream>>>(q, k, v, partO, partL);

    post_pool<<<dim3(4, BB), 256, 0, stream>>>(partO, partL, tsplit,
        lna2_g, lna2_b, ln2_g, ln2_b, poolp);

    final_kernel<<<1, 512, 0, stream>>>(poolp, out_w, out_b, out);
}